// Round 3
// baseline (173.637 us; speedup 1.0000x reference)
//
#include <hip/hip_runtime.h>
#include <hip/hip_cooperative_groups.h>
#include <math.h>

namespace cg = cooperative_groups;

#define HH 32
#define WW 32
#define CIN 64
#define NO 64
#define NCK 576                 // CIN*9
#define X_ELEMS 262144
#define STRIDE_E 296            // LDS worklist entries per pixel-half (288+pad to 8, 16B-aligned rows)

// ws float-offsets
#define WS_W    0               // Wz[ck][o] = -SZ*theta[o][ck]  (36864, coalesced in o)
#define WS_TAU  36864           // tau[ck] = SZ*min_o theta - 8, +64 pad(1e30)

__device__ __forceinline__ float fexp2(float x) {
#if __has_builtin(__builtin_amdgcn_exp2f)
    return __builtin_amdgcn_exp2f(x);
#else
    return exp2f(x);
#endif
}
__device__ __forceinline__ float flog2(float x) {
#if __has_builtin(__builtin_amdgcn_logf)
    return __builtin_amdgcn_logf(x);
#else
    return log2f(x);
#endif
}

// Single cooperative kernel: 512 blocks x 512 thr, exactly 2 blocks/CU
// co-resident (launch_bounds caps VGPR at 128, LDS 23KB). Blocks 0..71
// run the prep transform (W transpose + tau col-min), grid.sync, then
// every wave runs 2 pixel-half units (Phase A worklist build + Phase B
// octet evaluation). Saves one dispatch + inter-kernel gap per iteration.
__global__ __launch_bounds__(512, 4) void ekv_fused(
        const float* __restrict__ x, const float* __restrict__ theta,
        float* __restrict__ ws, float* __restrict__ out) {
    constexpr float SZ = 19.235933878519512f;    // log2(e)/0.075
    constexpr float C2 = 1.2726342e-3f;          // 2^(-D2), D2 = 0.5/(0.075*ln2)
    constexpr float OS = 0.020018875579925058f;  // ln2^2 * 2e-6 * 500000/24

    __shared__ int   lc[8][STRIDE_E];            // ck worklists (per wave, reused across units)
    __shared__ float lx[8][STRIDE_E];            // xs worklists
    __shared__ float pp[16][64];                 // per-unit partials (epilogue)

    const int t    = threadIdx.x;
    const int lane = t & 63;
    const int wv   = __builtin_amdgcn_readfirstlane(t >> 6);  // 0..7
    const int bb   = (int)blockIdx.x;

    // ---- Prep phase (blocks 0..72): W transpose + tau, then grid-wide sync
    if (bb < 72) {
        int i = bb * 512 + t;                    // i = ck*64 + o; lanes are o
        int o = i & 63, ck = i >> 6;
        float th = theta[o * NCK + ck];
        ws[WS_W + i] = -SZ * th;
        float mn = th;                           // wave-min over the 64 o's
#pragma unroll
        for (int s = 32; s > 0; s >>= 1)
            mn = fminf(mn, __shfl_xor(mn, s, 64));
        if (o == 0) ws[WS_TAU + ck] = SZ * mn - 8.0f;   // active iff z >= -8
    } else if (bb == 72) {
        if (t < 64) ws[WS_TAU + NCK + t] = 1e30f;       // tau pad: never active
    }
    __threadfence();
    cg::this_grid().sync();

    // ---- Main phase: 2 pixel-half units per wave ----
    for (int unit = 0; unit < 2; ++unit) {
        const int p2  = bb * 16 + wv + unit * 8; // pixel-half id
        const int pix = p2 >> 1, half = p2 & 1;
        const int n  = pix >> 10;
        const int ho = (pix >> 5) & 31;
        const int wo = pix & 31;
        const int c0 = half * 32;

        // ---- Phase A: build this wave's worklist in LDS ----
        int l = lane;
        int c_off = l / 9; if (c_off > 6) c_off = 6;
        int k = l - 9 * c_off; if (k > 8) k = 8;
        int di = k / 3, dj = k - 3 * (k / 3);
        int h = ho + di - 1, w_ = wo + dj - 1;
        bool sval = (h >= 0) && (h < HH) && (w_ >= 0) && (w_ < WW);
        int hc = min(max(h, 0), HH - 1), wc = min(max(w_, 0), WW - 1);
        // pad taps: xs = 0 == exact x=0 contribution if ever active; else skipped
        float msc = ((l < 63) && sval) ? SZ : 0.0f;

        int gidx = n * (CIN * HH * WW) + (c0 + c_off) * 1024 + hc * WW + wc;
        const float* tw = ws + WS_TAU + c0 * 9;

        int cnt = 0;
        float xv = x[min(gidx, X_ELEMS - 1)];    // chunk 0 (OOB lanes masked)
        float tv = tw[l];

        for (int cb = 0; cb < 32; cb += 7) {
            int cc = 32 - cb; if (cc > 7) cc = 7;
            int gidx2 = gidx + 7 * 1024;
            const float* tw2 = tw + 63;
            float xvn = xv, tvn = tv;
            if (cb + 7 < 32) { xvn = x[min(gidx2, X_ELEMS - 1)]; tvn = tw2[l]; }

            float xs = xv * msc;                 // SZ*x (pad lanes: 0)
            bool a = (xs >= tv) && (l < cc * 9);
            unsigned long long act = __ballot(a);
            unsigned lo32 = (unsigned)act, hi32 = (unsigned)(act >> 32);
            int idx = __builtin_amdgcn_mbcnt_hi(hi32,
                          __builtin_amdgcn_mbcnt_lo(lo32, 0));
            if (a) {
                lc[wv][cnt + idx] = (c0 + cb) * 9 + l;   // ck
                lx[wv][cnt + idx] = xs;                  // SZ*x
            }
            cnt += (int)__popcll(act);           // uniform across lanes
            gidx = gidx2; tw = tw2; xv = xvn; tv = tvn;
        }
        // pad to a multiple of 8 with exact-zero dummies (z=-1e5 -> exp2 -> 0)
        int padn = (-cnt) & 7;
        if (lane < padn) { lc[wv][cnt + lane] = 0; lx[wv][cnt + lane] = -100000.0f; }
        const int rounds = (cnt + padn) >> 3;    // uniform

        // ---- Phase B: fixed-trip octet evaluation over this wave's list ----
        const int4*   LC = (const int4*)&lc[wv][0];  // rows are 16B-aligned (296*4)
        const float4* LX = (const float4*)&lx[wv][0];
        const float* wsW = ws + WS_W + lane;

        float accF0 = 0.f, accR0 = 0.f, accF1 = 0.f, accR1 = 0.f;

#define EKV_BODY(SX, WV, AF, AR)                                           \
        {                                                                  \
            float z  = (WV) + (SX);      /* SZ*(x - theta) */              \
            float e  = fexp2(z);                                           \
            float f  = flog2(1.0f + e);                                    \
            float rr = flog2(fmaf(C2, e, 1.0f));                           \
            AF = fmaf(f, f, AF);                                           \
            AR = fmaf(rr, rr, AR);                                         \
        }

        if (rounds > 0) {
            int4   ca = LC[0], cb4 = LC[1];
            float4 xa = LX[0], xb = LX[1];
            for (int r = 0; r < rounds; ++r) {
                int4 can = ca, cbn = cb4; float4 xan = xa, xbn = xb;
                if (r + 1 < rounds) {
                    can = LC[2 * r + 2]; cbn = LC[2 * r + 3];
                    xan = LX[2 * r + 2]; xbn = LX[2 * r + 3];
                }
                // 8 coalesced W-row loads issued before any body
                float W0 = wsW[ca.x  << 6];
                float W1 = wsW[ca.y  << 6];
                float W2 = wsW[ca.z  << 6];
                float W3 = wsW[ca.w  << 6];
                float W4 = wsW[cb4.x << 6];
                float W5 = wsW[cb4.y << 6];
                float W6 = wsW[cb4.z << 6];
                float W7 = wsW[cb4.w << 6];
                EKV_BODY(xa.x, W0, accF0, accR0)
                EKV_BODY(xa.y, W1, accF1, accR1)
                EKV_BODY(xa.z, W2, accF0, accR0)
                EKV_BODY(xa.w, W3, accF1, accR1)
                EKV_BODY(xb.x, W4, accF0, accR0)
                EKV_BODY(xb.y, W5, accF1, accR1)
                EKV_BODY(xb.z, W6, accF0, accR0)
                EKV_BODY(xb.w, W7, accF1, accR1)
                ca = can; cb4 = cbn; xa = xan; xb = xbn;
            }
        }
#undef EKV_BODY

        pp[wv + unit * 8][lane] = (accF0 + accF1) - (accR0 + accR1);
    }

    // ---- Epilogue: one wave stores 8 consecutive wo as 2x float4 ----
    __syncthreads();
    if (t < 64) {                                // lane = o
        float s0 = (pp[ 0][t] + pp[ 1][t]) * OS;
        float s1 = (pp[ 2][t] + pp[ 3][t]) * OS;
        float s2 = (pp[ 4][t] + pp[ 5][t]) * OS;
        float s3 = (pp[ 6][t] + pp[ 7][t]) * OS;
        float s4 = (pp[ 8][t] + pp[ 9][t]) * OS;
        float s5 = (pp[10][t] + pp[11][t]) * OS;
        float s6 = (pp[12][t] + pp[13][t]) * OS;
        float s7 = (pp[14][t] + pp[15][t]) * OS;
        int pixb = bb * 8;                       // 8 consecutive wo in one (n, ho)
        int nn = pixb >> 10, hh = (pixb >> 5) & 31, w0 = pixb & 31;
        float* po = &out[((nn * NO + t) * HH + hh) * WW + w0];
        *(float4*)(po)     = make_float4(s0, s1, s2, s3);
        *(float4*)(po + 4) = make_float4(s4, s5, s6, s7);
    }
}

extern "C" void kernel_launch(void* const* d_in, const int* in_sizes, int n_in,
                              void* d_out, int out_size, void* d_ws, size_t ws_size,
                              hipStream_t stream) {
    const float* x     = (const float*)d_in[0];   // (4,64,32,32) fp32
    const float* theta = (const float*)d_in[1];   // (64,64,3,3) fp32
    float* out = (float*)d_out;                   // (4,64,32,32) fp32
    float* ws  = (float*)d_ws;

    void* args[] = { (void*)&x, (void*)&theta, (void*)&ws, (void*)&out };
    hipLaunchCooperativeKernel((const void*)ekv_fused, dim3(512), dim3(512),
                               args, 0, stream);
}

// Round 4
// 73.151 us; speedup vs baseline: 2.3737x; 2.3737x over previous
//
#include <hip/hip_runtime.h>
#include <math.h>

#define HH 32
#define WW 32
#define CIN 64
#define NO 64
#define NCK 576                 // CIN*9
#define X_ELEMS 262144
#define STRIDE_E 296            // LDS worklist entries per pixel-half (288+pad to 8, 16B-aligned rows)

// ws float-offsets
#define WS_W    0               // Wz[ck][o] = -SZ*theta[o][ck]  (36864, coalesced in o)
#define WS_TAU  36864           // tau[ck] = SZ*min_o theta - 8, +64 pad(1e30)

__device__ __forceinline__ float fexp2(float x) {
#if __has_builtin(__builtin_amdgcn_exp2f)
    return __builtin_amdgcn_exp2f(x);
#else
    return exp2f(x);
#endif
}
__device__ __forceinline__ float flog2(float x) {
#if __has_builtin(__builtin_amdgcn_logf)
    return __builtin_amdgcn_logf(x);
#else
    return log2f(x);
#endif
}

__global__ __launch_bounds__(256) void prep_kernel(const float* __restrict__ theta,
                                                   float* __restrict__ ws) {
    constexpr float SZ = 19.235933878519512f;    // log2(e)/0.075
    const int b = blockIdx.x, t = threadIdx.x;
    if (b < 144) {                               // W transform + in-wave tau min
        int i = b * 256 + t;                     // i = ck*64 + o; lanes are o
        int o = i & 63, ck = i >> 6;
        float th = theta[o * NCK + ck];
        ws[WS_W + i] = -SZ * th;
        float mn = th;                           // wave-min over the 64 o's
#pragma unroll
        for (int s = 32; s > 0; s >>= 1)
            mn = fminf(mn, __shfl_xor(mn, s, 64));
        if (o == 0) ws[WS_TAU + ck] = SZ * mn - 8.0f;   // active iff z >= -8
    } else {                                     // tau pad: never active
        if (t < 64) ws[WS_TAU + NCK + t] = 1e30f;
    }
}

// Single main kernel: block = 512 thr = 8 waves = 4 pixels x 2 c-halves.
// Phase A (per wave, no barrier needed -- wave consumes its own list): test
// 7ch x 9taps per ballot, mbcnt-compact actives into an LDS worklist.
// Phase B (per wave): fixed-trip loop over worklist OCTETS (uniform
// ds_read_b128 x2, prefetched), 8 pipelined global W-row loads + 8
// exp2/log2 bodies per round on 4 split accumulators (breaks the 4-cy
// FMA dependence chain). No ballot/ctz/readlane in the evaluation loop.
// Epilogue: LDS transpose of the 8 wave-partials, one wave stores
// float4 (4 consecutive wo per block) instead of 256 scattered dwords.
// NOTE (R3): do NOT fuse these via hipLaunchCooperativeKernel — grid.sync()
// on a 512-block coop launch measured ~90 us of pure stall on MI355X.
__global__ __launch_bounds__(512) void ekv_kernel(
        const float* __restrict__ x, const float* __restrict__ ws,
        float* __restrict__ out) {
    constexpr float SZ = 19.235933878519512f;    // log2(e)/0.075
    constexpr float C2 = 1.2726342e-3f;          // 2^(-D2), D2 = 0.5/(0.075*ln2)
    constexpr float OS = 0.020018875579925058f;  // ln2^2 * 2e-6 * 500000/24

    __shared__ int   lc[8][STRIDE_E];            // ck worklists (per wave)
    __shared__ float lx[8][STRIDE_E];            // xs worklists
    __shared__ float pp[8][64];                  // per-wave partials (epilogue)

    const int t    = threadIdx.x;
    const int lane = t & 63;
    const int wv   = __builtin_amdgcn_readfirstlane(t >> 6);  // 0..7
    const int p2   = (int)blockIdx.x * 8 + wv;   // pixel-half id
    const int pix  = p2 >> 1, half = p2 & 1;
    const int n  = pix >> 10;
    const int ho = (pix >> 5) & 31;
    const int wo = pix & 31;
    const int c0 = half * 32;

    // ---- Phase A: build this wave's worklist in LDS ----
    int l = lane;
    int c_off = l / 9; if (c_off > 6) c_off = 6;
    int k = l - 9 * c_off; if (k > 8) k = 8;
    int di = k / 3, dj = k - 3 * (k / 3);
    int h = ho + di - 1, w_ = wo + dj - 1;
    bool sval = (h >= 0) && (h < HH) && (w_ >= 0) && (w_ < WW);
    int hc = min(max(h, 0), HH - 1), wc = min(max(w_, 0), WW - 1);
    // pad taps: xs = 0 == exact x=0 contribution if ever active; else skipped
    float msc = ((l < 63) && sval) ? SZ : 0.0f;

    int gidx = n * (CIN * HH * WW) + (c0 + c_off) * 1024 + hc * WW + wc;
    const float* tw = ws + WS_TAU + c0 * 9;

    int cnt = 0;
    float xv = x[min(gidx, X_ELEMS - 1)];        // chunk 0 (OOB lanes masked)
    float tv = tw[l];

    for (int cb = 0; cb < 32; cb += 7) {
        int cc = 32 - cb; if (cc > 7) cc = 7;
        int gidx2 = gidx + 7 * 1024;
        const float* tw2 = tw + 63;
        float xvn = xv, tvn = tv;
        if (cb + 7 < 32) { xvn = x[min(gidx2, X_ELEMS - 1)]; tvn = tw2[l]; }

        float xs = xv * msc;                     // SZ*x (pad lanes: 0)
        bool a = (xs >= tv) && (l < cc * 9);
        unsigned long long act = __ballot(a);
        unsigned lo32 = (unsigned)act, hi32 = (unsigned)(act >> 32);
        int idx = __builtin_amdgcn_mbcnt_hi(hi32,
                      __builtin_amdgcn_mbcnt_lo(lo32, 0));
        if (a) {
            lc[wv][cnt + idx] = (c0 + cb) * 9 + l;   // ck
            lx[wv][cnt + idx] = xs;                  // SZ*x
        }
        cnt += (int)__popcll(act);               // uniform across lanes
        gidx = gidx2; tw = tw2; xv = xvn; tv = tvn;
    }
    // pad to a multiple of 8 with exact-zero dummies (z=-1e5 -> exp2 -> 0)
    int padn = (-cnt) & 7;
    if (lane < padn) { lc[wv][cnt + lane] = 0; lx[wv][cnt + lane] = -100000.0f; }
    const int rounds = (cnt + padn) >> 3;        // uniform

    // ---- Phase B: fixed-trip octet evaluation over this wave's list ----
    const int4*   LC = (const int4*)&lc[wv][0];  // rows are 16B-aligned (296*4)
    const float4* LX = (const float4*)&lx[wv][0];
    const float* wsW = ws + WS_W + lane;

    float accF0 = 0.f, accR0 = 0.f, accF1 = 0.f, accR1 = 0.f;

#define EKV_BODY(SX, WV, AF, AR)                                           \
    {                                                                      \
        float z  = (WV) + (SX);      /* SZ*(x - theta) */                  \
        float e  = fexp2(z);                                               \
        float f  = flog2(1.0f + e);                                        \
        float rr = flog2(fmaf(C2, e, 1.0f));                               \
        AF = fmaf(f, f, AF);                                               \
        AR = fmaf(rr, rr, AR);                                             \
    }

    if (rounds > 0) {
        int4   ca = LC[0], cb4 = LC[1];
        float4 xa = LX[0], xb = LX[1];
        for (int r = 0; r < rounds; ++r) {
            int4 can = ca, cbn = cb4; float4 xan = xa, xbn = xb;
            if (r + 1 < rounds) {
                can = LC[2 * r + 2]; cbn = LC[2 * r + 3];
                xan = LX[2 * r + 2]; xbn = LX[2 * r + 3];
            }
            // 8 coalesced W-row loads issued before any body; body k only
            // waits vmcnt for its own row (natural software pipeline)
            float W0 = wsW[ca.x  << 6];
            float W1 = wsW[ca.y  << 6];
            float W2 = wsW[ca.z  << 6];
            float W3 = wsW[ca.w  << 6];
            float W4 = wsW[cb4.x << 6];
            float W5 = wsW[cb4.y << 6];
            float W6 = wsW[cb4.z << 6];
            float W7 = wsW[cb4.w << 6];
            EKV_BODY(xa.x, W0, accF0, accR0)
            EKV_BODY(xa.y, W1, accF1, accR1)
            EKV_BODY(xa.z, W2, accF0, accR0)
            EKV_BODY(xa.w, W3, accF1, accR1)
            EKV_BODY(xb.x, W4, accF0, accR0)
            EKV_BODY(xb.y, W5, accF1, accR1)
            EKV_BODY(xb.z, W6, accF0, accR0)
            EKV_BODY(xb.w, W7, accF1, accR1)
            ca = can; cb4 = cbn; xa = xan; xb = xbn;
        }
    }
#undef EKV_BODY

    // ---- Epilogue: transpose partials in LDS, one wave does float4 stores
    pp[wv][lane] = (accF0 + accF1) - (accR0 + accR1);
    __syncthreads();
    if (t < 64) {                                // wave 0, lane = o
        // wave wv: px = wv>>1, half = wv&1  ->  pixel px sum = pp[2px]+pp[2px+1]
        float s0 = (pp[0][t] + pp[1][t]) * OS;
        float s1 = (pp[2][t] + pp[3][t]) * OS;
        float s2 = (pp[4][t] + pp[5][t]) * OS;
        float s3 = (pp[6][t] + pp[7][t]) * OS;
        // block covers 4 consecutive wo in one (n, ho); 16B-aligned since wo0 % 4 == 0
        int pixb = (int)blockIdx.x * 4;
        int nn = pixb >> 10, hh = (pixb >> 5) & 31, w0 = pixb & 31;
        float4 v = make_float4(s0, s1, s2, s3);
        *(float4*)&out[((nn * NO + t) * HH + hh) * WW + w0] = v;
    }
}

extern "C" void kernel_launch(void* const* d_in, const int* in_sizes, int n_in,
                              void* d_out, int out_size, void* d_ws, size_t ws_size,
                              hipStream_t stream) {
    const float* x     = (const float*)d_in[0];   // (4,64,32,32) fp32
    const float* theta = (const float*)d_in[1];   // (64,64,3,3) fp32
    float* out = (float*)d_out;                   // (4,64,32,32) fp32
    float* ws  = (float*)d_ws;

    prep_kernel<<<145, 256, 0, stream>>>(theta, ws);
    ekv_kernel <<<1024, 512, 0, stream>>>(x, ws, out);  // build+eval fused
}